// Round 4
// baseline (1119.276 us; speedup 1.0000x reference)
//
#include <hip/hip_runtime.h>

#define DEV static __device__ __forceinline__

// ---------------------------------------------------------------------------
// CORRECTNESS ROUND: pure-VALU f32 everywhere, f32 OUTPUT (reference returns
// jnp.float32; harness doc: output dtype follows reference -> float*).
// ---------------------------------------------------------------------------

// vk_init: slots = mu + (softplus(lsg)+1e-5)*noise; q0 = 0.125*(LN_sl(slots)@Wq^T)
// zero U,S. 32 blocks x 64 thr.
__global__ __launch_bounds__(64) void vk_init(
    const float* __restrict__ noise, const float* __restrict__ mu,
    const float* __restrict__ lsg,
    const float* __restrict__ gsl, const float* __restrict__ bsl,
    const float* __restrict__ Wq,
    float* __restrict__ slots, float* __restrict__ qf,
    float* __restrict__ U, float* __restrict__ S)
{
  const int b = blockIdx.x, ln = threadIdx.x;
  const float gv = gsl[ln], bv = bsl[ln];
  for (int k = 0; k < 8; ++k){
    float sl = mu[k*64+ln] + (log1pf(expf(lsg[k*64+ln])) + 1e-5f) * noise[(b*8+k)*64+ln];
    slots[(b*8+k)*64+ln] = sl;
    float s1 = sl, s2 = sl*sl;
    #pragma unroll
    for (int m = 32; m >= 1; m >>= 1){ s1 += __shfl_xor(s1,m); s2 += __shfl_xor(s2,m); }
    float mean = s1*(1.f/64.f), var = s2*(1.f/64.f) - mean*mean;
    float sn = (sl-mean)*rsqrtf(var+1e-5f)*gv + bv;
    float qv = 0.f;
    #pragma unroll 8
    for (int h = 0; h < 64; ++h) qv += __shfl(sn,h) * Wq[ln*64+h];
    qf[(b*8+k)*64+ln] = qv * 0.125f;   // fold H^-0.5
  }
  #pragma unroll
  for (int i = 0; i < 8; ++i) U[b*512 + i*64 + ln] = 0.f;
  if (ln < 8) S[b*8+ln] = 0.f;
}

// vk_attn: per (b, 64-row n-chunk): LN(x) -> k,v (recomputed, VALU f32),
// scores -> softmax+eps -> accumulate U = sum(a*v), S = sum(a) via atomics.
// 2048 blocks x 256 thr.
__global__ __launch_bounds__(256) void vk_attn(
    const float* __restrict__ x,
    const float* __restrict__ Wk, const float* __restrict__ Wv,
    const float* __restrict__ lg, const float* __restrict__ lb,
    const float* __restrict__ qf,
    float* __restrict__ U, float* __restrict__ S)
{
  __shared__ float xr[16*132];
  __shared__ float kL[64*68];
  __shared__ float vL[64*68];
  __shared__ float qL[512];
  __shared__ float scL[64*12];
  const int tid = threadIdx.x;
  const int b = blockIdx.x >> 6;
  const int nbase = (blockIdx.x & 63) << 6;
  const int w = tid >> 6, ln = tid & 63;
  const int h = tid & 63, rq = tid >> 6;

  for (int idx = tid; idx < 512; idx += 256) qL[idx] = qf[b*512 + idx];

  for (int rb = 0; rb < 4; ++rb){
    __syncthreads();                 // xr safe to overwrite
    #pragma unroll
    for (int j2 = 0; j2 < 2; ++j2){  // load 16 rows x 128 f32 of x
      int idx = tid*8 + j2*4;
      int r = idx >> 7, d = idx & 127;
      *(float4*)&xr[r*132 + d] =
          *(const float4*)&x[((long)b*4096 + nbase + rb*16 + r)*128 + d];
    }
    __syncthreads();
    // LN in place: wave w handles rows w, w+4, w+8, w+12
    #pragma unroll
    for (int p = 0; p < 4; ++p){
      int r = p*4 + w;
      float v0 = xr[r*132 + ln], v1 = xr[r*132 + 64 + ln];
      float s1 = v0+v1, s2 = v0*v0+v1*v1;
      #pragma unroll
      for (int m = 32; m >= 1; m >>= 1){ s1 += __shfl_xor(s1,m); s2 += __shfl_xor(s2,m); }
      float mean = s1*(1.f/128.f), var = s2*(1.f/128.f) - mean*mean;
      float rs = rsqrtf(var + 1e-5f);
      xr[r*132 + ln]      = (v0-mean)*rs*lg[ln]    + lb[ln];
      xr[r*132 + 64 + ln] = (v1-mean)*rs*lg[64+ln] + lb[64+ln];
    }
    __syncthreads();
    // projections: thread (rq,h) -> rows rb*16 + rq + 4i, output feature h
    float aK[4] = {0,0,0,0}, aV[4] = {0,0,0,0};
    for (int dc = 0; dc < 32; ++dc){
      float4 wk4 = *(const float4*)&Wk[h*128 + dc*4];
      float4 wv4 = *(const float4*)&Wv[h*128 + dc*4];
      #pragma unroll
      for (int i = 0; i < 4; ++i){
        float4 xv = *(const float4*)&xr[(rq + i*4)*132 + dc*4];
        aK[i] += xv.x*wk4.x + xv.y*wk4.y + xv.z*wk4.z + xv.w*wk4.w;
        aV[i] += xv.x*wv4.x + xv.y*wv4.y + xv.z*wv4.z + xv.w*wv4.w;
      }
    }
    #pragma unroll
    for (int i = 0; i < 4; ++i){
      kL[(rb*16 + rq + i*4)*68 + h] = aK[i];
      vL[(rb*16 + rq + i*4)*68 + h] = aV[i];
    }
  }
  __syncthreads();
  // scores[r][slot] = sum_h k*q (q pre-scaled by 0.125)
  {
    int r = tid >> 2, j0 = tid & 3;
    float s0 = 0.f, s1 = 0.f;
    for (int hh = 0; hh < 64; ++hh){
      float kv = kL[r*68 + hh];
      s0 += kv * qL[j0*64 + hh];
      s1 += kv * qL[(j0+4)*64 + hh];
    }
    scL[r*12 + j0]     = s0;
    scL[r*12 + j0 + 4] = s1;
  }
  __syncthreads();
  // softmax over 8 slots + 1e-8, in place
  if (tid < 64){
    float a8[8], mx = -1e30f;
    #pragma unroll
    for (int j = 0; j < 8; ++j){ a8[j] = scL[tid*12+j]; mx = fmaxf(mx, a8[j]); }
    float ss = 0.f;
    #pragma unroll
    for (int j = 0; j < 8; ++j){ a8[j] = expf(a8[j]-mx); ss += a8[j]; }
    float inv = 1.f/ss;
    #pragma unroll
    for (int j = 0; j < 8; ++j) scL[tid*12+j] = a8[j]*inv + 1e-8f;
  }
  __syncthreads();
  // S[b][slot] += column sums
  {
    int sl = tid >> 5, c = tid & 31;
    float p = scL[c*12 + sl] + scL[(c+32)*12 + sl];
    #pragma unroll
    for (int m = 16; m >= 1; m >>= 1) p += __shfl_xor(p, m);
    if ((ln & 31) == 0) atomicAdd(&S[b*8 + sl], p);
  }
  // U[b][slot][h] += sum_r a[r][slot]*v[r][h]
  {
    int sl = tid >> 5, hh = tid & 31;
    float a0 = 0.f, a1 = 0.f;
    for (int r = 0; r < 64; ++r){
      float av = scL[r*12 + sl];
      a0 += av * vL[r*68 + hh];
      a1 += av * vL[r*68 + 32 + hh];
    }
    atomicAdd(&U[b*512 + sl*64 + hh], a0);
    atomicAdd(&U[b*512 + sl*64 + 32 + hh], a1);
  }
}

// vk_gru: GRU + LN_mlp + MLP + residual + LN_sl + next q. 16 blocks x 256 thr.
__global__ __launch_bounds__(256) void vk_gru(
    const float* __restrict__ U, const float* __restrict__ S,
    float* __restrict__ slots,
    const float* __restrict__ wih, const float* __restrict__ whh,
    const float* __restrict__ bih, const float* __restrict__ bhh,
    const float* __restrict__ w1, const float* __restrict__ b1,
    const float* __restrict__ w2, const float* __restrict__ b2,
    const float* __restrict__ gm, const float* __restrict__ bm,
    const float* __restrict__ gsl, const float* __restrict__ bsl,
    const float* __restrict__ Wq, float* __restrict__ qf,
    float* __restrict__ outp,
    float* __restrict__ Uz, float* __restrict__ Sz)
{
  __shared__ float uL[16*68], hL[16*68], spL[16*68], stL[16*68], snL[16*68], sqL[16*68];
  __shared__ float hidL[16*132];
  __shared__ float redA[16*20], redB[16*20];
  const int tid = threadIdx.x;
  const int row = tid >> 4, c16 = tid & 15;
  const int r0 = blockIdx.x * 16;

  #pragma unroll
  for (int j = 0; j < 4; ++j){
    int c = c16 + 16*j;
    uL[row*68 + c] = U[(r0+row)*64 + c] / S[r0+row];
    hL[row*68 + c] = slots[(r0+row)*64 + c];
  }
  __syncthreads();
  // GRU gates (PyTorch r,z,n order)
  for (int j = 0; j < 4; ++j){
    int c = c16 + 16*j;
    float xr=0, xz=0, xn=0, hr=0, hz=0, hn=0;
    for (int hh = 0; hh < 64; ++hh){
      float uv = uL[row*68+hh], hv = hL[row*68+hh];
      xr += uv * wih[c*64+hh];
      xz += uv * wih[(64+c)*64+hh];
      xn += uv * wih[(128+c)*64+hh];
      hr += hv * whh[c*64+hh];
      hz += hv * whh[(64+c)*64+hh];
      hn += hv * whh[(128+c)*64+hh];
    }
    xr += bih[c];     hr += bhh[c];
    xz += bih[64+c];  hz += bhh[64+c];
    xn += bih[128+c]; hn += bhh[128+c];
    float rg = 1.f/(1.f+expf(-(xr+hr)));
    float zg = 1.f/(1.f+expf(-(xz+hz)));
    float ng = tanhf(xn + rg*hn);
    spL[row*68+c] = (1.f-zg)*ng + zg*hL[row*68+c];
  }
  __syncthreads();
  // LN_mlp
  {
    float ps=0, pq=0;
    #pragma unroll
    for (int j = 0; j < 4; ++j){ float v = spL[row*68 + c16 + 16*j]; ps += v; pq += v*v; }
    redA[row*20+c16] = ps; redB[row*20+c16] = pq;
  }
  __syncthreads();
  {
    float ts=0, tq=0;
    #pragma unroll
    for (int i = 0; i < 16; ++i){ ts += redA[row*20+i]; tq += redB[row*20+i]; }
    float mean = ts*(1.f/64.f), var = tq*(1.f/64.f) - mean*mean;
    float rs = rsqrtf(var+1e-5f);
    #pragma unroll
    for (int j = 0; j < 4; ++j){
      int c = c16+16*j;
      stL[row*68+c] = (spL[row*68+c]-mean)*rs*gm[c] + bm[c];
    }
  }
  __syncthreads();
  // mlp1 (64->128) + relu
  for (int j = 0; j < 8; ++j){
    int col = c16 + 16*j;
    float acc = 0;
    for (int hh = 0; hh < 64; ++hh) acc += stL[row*68+hh]*w1[col*64+hh];
    hidL[row*132+col] = fmaxf(acc + b1[col], 0.f);
  }
  __syncthreads();
  // mlp2 (128->64) + residual; write slots + output (f32)
  for (int j = 0; j < 4; ++j){
    int c = c16+16*j;
    float acc = 0;
    for (int m = 0; m < 128; ++m) acc += hidL[row*132+m]*w2[c*128+m];
    float sn = stL[row*68+c] + acc + b2[c];
    snL[row*68+c] = sn;
    slots[(r0+row)*64+c] = sn;
    outp[(r0+row)*64+c] = sn;
  }
  __syncthreads();
  // LN_sl(snew) -> sqL
  {
    float ps=0, pq=0;
    #pragma unroll
    for (int j = 0; j < 4; ++j){ float v = snL[row*68+c16+16*j]; ps += v; pq += v*v; }
    redA[row*20+c16] = ps; redB[row*20+c16] = pq;
  }
  __syncthreads();
  {
    float ts=0, tq=0;
    #pragma unroll
    for (int i = 0; i < 16; ++i){ ts += redA[row*20+i]; tq += redB[row*20+i]; }
    float mean = ts*(1.f/64.f), var = tq*(1.f/64.f)-mean*mean;
    float rs = rsqrtf(var+1e-5f);
    #pragma unroll
    for (int j = 0; j < 4; ++j){
      int c = c16+16*j;
      sqL[row*68+c] = (snL[row*68+c]-mean)*rs*gsl[c] + bsl[c];
    }
  }
  __syncthreads();
  // next-iteration q (pre-scaled); zero U for next iter
  for (int j = 0; j < 4; ++j){
    int c = c16+16*j;
    float acc = 0;
    for (int hh = 0; hh < 64; ++hh) acc += sqL[row*68+hh]*Wq[c*64+hh];
    qf[(r0+row)*64+c] = acc*0.125f;
    Uz[(r0+row)*64+c] = 0.f;
  }
  if (tid < 16) Sz[r0+tid] = 0.f;
}

// sentinel: writes an error code into out[0] if host-side size checks failed
__global__ void vk_sentinel(float* __restrict__ outp, float code)
{
  outp[0] = code;
}

// ---------------------------------------------------------------------------
extern "C" void kernel_launch(void* const* d_in, const int* in_sizes, int n_in,
                              void* d_out, int out_size, void* d_ws, size_t ws_size,
                              hipStream_t stream)
{
  const float* x    = (const float*)d_in[0];
  const float* noise= (const float*)d_in[1];
  const float* Wq   = (const float*)d_in[2];
  const float* Wk   = (const float*)d_in[3];
  const float* Wv   = (const float*)d_in[4];
  const float* ling = (const float*)d_in[5];
  const float* linb = (const float*)d_in[6];
  const float* gsl  = (const float*)d_in[7];
  const float* bsl  = (const float*)d_in[8];
  const float* gmlp = (const float*)d_in[9];
  const float* bmlp = (const float*)d_in[10];
  const float* wih  = (const float*)d_in[11];
  const float* whh  = (const float*)d_in[12];
  const float* bih  = (const float*)d_in[13];
  const float* bhh  = (const float*)d_in[14];
  const float* w1   = (const float*)d_in[15];
  const float* b1   = (const float*)d_in[16];
  const float* w2   = (const float*)d_in[17];
  const float* b2   = (const float*)d_in[18];
  const float* mu   = (const float*)d_in[19];
  const float* lsg  = (const float*)d_in[20];

  char* ws = (char*)d_ws;
  float* qf    = (float*)(ws);            // 64 KB  q [32][8][64] f32 (0.125-scaled)
  float* slots = (float*)(ws + 65536);    // 64 KB
  float* U     = (float*)(ws + 131072);   // 64 KB
  float* S     = (float*)(ws + 196608);   // 1 KB
  float* outp  = (float*)d_out;

  hipLaunchKernelGGL(vk_init, dim3(32), dim3(64), 0, stream,
                     noise, mu, lsg, gsl, bsl, Wq, slots, qf, U, S);
  for (int it = 0; it < 3; ++it){
    hipLaunchKernelGGL(vk_attn, dim3(2048), dim3(256), 0, stream,
                       x, Wk, Wv, ling, linb, qf, U, S);
    hipLaunchKernelGGL(vk_gru, dim3(16), dim3(256), 0, stream,
                       U, S, slots, wih, whh, bih, bhh, w1, b1, w2, b2,
                       gmlp, bmlp, gsl, bsl, Wq, qf, outp, U, S);
  }

  // Host-side sanity sentinel (deterministic across calls -> capture-safe).
  // If any size assumption is wrong, absmax becomes ~1000+100*i, a readable code.
  static const int expect[21] = {16777216,16384,4096,8192,8192,128,128,64,64,64,64,
                                 12288,12288,192,192,8192,128,8192,64,512,512};
  int bad = -1;
  if (n_in != 21) bad = 21;
  else {
    for (int i = 0; i < 21; ++i) if (in_sizes[i] != expect[i]) { bad = i; break; }
    if (bad < 0 && out_size != 16384) bad = 22;
  }
  if (bad >= 0)
    hipLaunchKernelGGL(vk_sentinel, dim3(1), dim3(1), 0, stream,
                       outp, 1000.f + 100.f*bad);
  (void)ws_size;
}

// Round 5
// 283.590 us; speedup vs baseline: 3.9468x; 3.9468x over previous
//
#include <hip/hip_runtime.h>

typedef __attribute__((ext_vector_type(8))) short s16x8;
typedef __attribute__((ext_vector_type(4))) float f32x4;

#define DEV static __device__ __forceinline__

DEV float b2f(unsigned short u){
  unsigned int i = ((unsigned int)u) << 16;
  float f; __builtin_memcpy(&f, &i, 4); return f;
}
DEV unsigned short f2b(float f){
  unsigned int i; __builtin_memcpy(&i, &f, 4);
  i = i + 0x7fffu + ((i >> 16) & 1u);
  return (unsigned short)(i >> 16);
}
DEV f32x4 mfma16(s16x8 a, s16x8 b, f32x4 c){
  return __builtin_amdgcn_mfma_f32_16x16x32_bf16(a, b, c, 0, 0, 0);
}
// load 8 consecutive f32 (32B-aligned) -> bf16 A/B fragment
DEV s16x8 ld8f(const float* p){
  const float4* q4 = (const float4*)p;
  float4 a = q4[0], b = q4[1];
  s16x8 r;
  r[0]=(short)f2b(a.x); r[1]=(short)f2b(a.y); r[2]=(short)f2b(a.z); r[3]=(short)f2b(a.w);
  r[4]=(short)f2b(b.x); r[5]=(short)f2b(b.y); r[6]=(short)f2b(b.z); r[7]=(short)f2b(b.w);
  return r;
}

// ---------------------------------------------------------------------------
// K1: LN(x) -> k = xn@Wk^T (plain [b][n][h] bf16), v = xn@Wv^T (transposed
// [b][h][n] bf16). x is f32. 1024 blocks x 256 thr, 128 rows/block.
// ---------------------------------------------------------------------------
__global__ __launch_bounds__(256) void k_lnkv(
    const float* __restrict__ x,
    const float* __restrict__ Wk,
    const float* __restrict__ Wv,
    const float* __restrict__ lg,
    const float* __restrict__ lb,
    unsigned short* __restrict__ kg,
    unsigned short* __restrict__ vt)
{
  __shared__ unsigned int xs[128 * 68];   // 128 rows x (64 data + 4 pad) uints (bf16 pairs)
  const int tid = threadIdx.x;
  const int w = tid >> 6, ln = tid & 63;
  const int m16 = ln & 15, q = ln >> 4;
  const int b = blockIdx.x >> 5;
  const int nbase = (blockIdx.x & 31) << 7;
  const long rowg0 = (long)b * 4096 + nbase;

  const float gl0 = lg[2*ln], gl1 = lg[2*ln+1];
  const float bl0 = lb[2*ln], bl1 = lb[2*ln+1];
  for (int i = 0; i < 32; ++i){
    int r = w*32 + i;
    float2 xv = ((const float2*)x)[(rowg0 + r)*64 + ln];
    float x0 = xv.x, x1 = xv.y;
    float s1 = x0 + x1, s2 = x0*x0 + x1*x1;
    #pragma unroll
    for (int m = 32; m >= 1; m >>= 1){
      s1 += __shfl_xor(s1, m);
      s2 += __shfl_xor(s2, m);
    }
    float mean = s1 * (1.f/128.f);
    float var  = s2 * (1.f/128.f) - mean*mean;
    float rs = rsqrtf(var + 1e-5f);
    float y0 = (x0 - mean)*rs*gl0 + bl0;
    float y1 = (x1 - mean)*rs*gl1 + bl1;
    xs[r*68 + ln] = (unsigned int)f2b(y0) | ((unsigned int)f2b(y1) << 16);
  }
  __syncthreads();

  // B-fragments: B[k=d][n'=h'] = Wc[h'][d]; nt 0..3 -> Wk rows, 4..7 -> Wv rows
  s16x8 bw[4][8];
  #pragma unroll
  for (int nt = 0; nt < 8; ++nt){
    const float* Wp = (nt < 4) ? (Wk + (nt*16 + m16)*128)
                               : (Wv + ((nt-4)*16 + m16)*128);
    #pragma unroll
    for (int kb = 0; kb < 4; ++kb)
      bw[kb][nt] = ld8f(Wp + kb*32 + q*8);
  }

  const f32x4 zf = {0.f, 0.f, 0.f, 0.f};
  #pragma unroll
  for (int mi = 0; mi < 2; ++mi){
    int n0 = (w*2 + mi) * 16;
    f32x4 acc[8];
    #pragma unroll
    for (int nt = 0; nt < 8; ++nt) acc[nt] = zf;
    #pragma unroll
    for (int kb = 0; kb < 4; ++kb){
      s16x8 af = *(const s16x8*)((const unsigned short*)(xs + (n0 + m16)*68) + kb*32 + q*8);
      #pragma unroll
      for (int nt = 0; nt < 8; ++nt)
        acc[nt] = mfma16(af, bw[kb][nt], acc[nt]);
    }
    // k: plain [b][n][h]; D row = q*4+rr, col = nt*16+m16
    #pragma unroll
    for (int nt = 0; nt < 4; ++nt){
      int h = nt*16 + m16;
      #pragma unroll
      for (int rr = 0; rr < 4; ++rr){
        long n = rowg0 + n0 + q*4 + rr;
        kg[n*64 + h] = f2b(acc[nt][rr]);
      }
    }
    // v: transposed [b][h][n]; the 4 regs are consecutive n -> one 8B store
    #pragma unroll
    for (int nt = 4; nt < 8; ++nt){
      int h = (nt-4)*16 + m16;
      unsigned int p0 = (unsigned int)f2b(acc[nt][0]) | ((unsigned int)f2b(acc[nt][1]) << 16);
      unsigned int p1 = (unsigned int)f2b(acc[nt][2]) | ((unsigned int)f2b(acc[nt][3]) << 16);
      uint2 pv; pv.x = p0; pv.y = p1;
      long off = ((long)b*64 + h)*4096 + nbase + n0 + q*4;
      *(uint2*)(vt + off) = pv;
    }
  }
}

// ---------------------------------------------------------------------------
// K2: slots = mu + (softplus(logsigma)+1e-5)*noise; q0 = 0.125 * Wq@LN_sl(slots)
// All inputs f32. Also zeroes q slot-pads (8..15) and U,S for iteration 0.
// ---------------------------------------------------------------------------
__global__ __launch_bounds__(64) void k_init(
    const float* __restrict__ noise,
    const float* __restrict__ mu,
    const float* __restrict__ lsg,
    const float* __restrict__ gsl,
    const float* __restrict__ bsl,
    const float* __restrict__ Wq,
    float* __restrict__ slots,
    unsigned short* __restrict__ qws,
    float* __restrict__ U, float* __restrict__ S)
{
  const int b = blockIdx.x, ln = threadIdx.x;
  const float gv = gsl[ln], bv = bsl[ln];
  for (int k = 0; k < 8; ++k){
    float muv = mu[k*64 + ln];
    float ls  = lsg[k*64 + ln];
    float scale = log1pf(expf(ls)) + 1e-5f;
    float nz = noise[(b*8 + k)*64 + ln];
    float sl = muv + scale*nz;
    slots[(b*8 + k)*64 + ln] = sl;
    float s1 = sl, s2 = sl*sl;
    #pragma unroll
    for (int m = 32; m >= 1; m >>= 1){
      s1 += __shfl_xor(s1, m);
      s2 += __shfl_xor(s2, m);
    }
    float mean = s1*(1.f/64.f);
    float var  = s2*(1.f/64.f) - mean*mean;
    float rs = rsqrtf(var + 1e-5f);
    float sn = (sl - mean)*rs*gv + bv;
    float qv = 0.f;
    #pragma unroll 8
    for (int h = 0; h < 64; ++h){
      float sh = __shfl(sn, h);
      qv += sh * Wq[ln*64 + h];
    }
    qws[(b*16 + k)*64 + ln] = f2b(qv * 0.125f);  // fold H^-0.5 into q
  }
  for (int k = 8; k < 16; ++k) qws[(b*16 + k)*64 + ln] = 0;
  #pragma unroll
  for (int i = 0; i < 8; ++i) U[b*512 + i*64 + ln] = 0.f;
  if (ln < 8) S[b*8 + ln] = 0.f;
}

// ---------------------------------------------------------------------------
// K3: attention pass. 512 blocks (b,chunk of 256 n) x 256 thr. MFMA for
// scores (A=k from global) and U-partials (B=v_t from global), softmax in LDS.
// ---------------------------------------------------------------------------
__global__ __launch_bounds__(256) void k_attn(
    const unsigned short* __restrict__ kg,
    const unsigned short* __restrict__ vt,
    const unsigned short* __restrict__ qws,
    float* __restrict__ U, float* __restrict__ S)
{
  __shared__ float sc[256*17];
  __shared__ unsigned short aT[16*264];   // stride 264 (=16B-aligned rows)
  const int tid = threadIdx.x;
  const int w = tid >> 6, ln = tid & 63;
  const int m16 = ln & 15, q = ln >> 4;
  const int b = blockIdx.x >> 4;
  const int nbase = (blockIdx.x & 15) << 8;

  for (int i = tid; i < 8*264; i += 256) aT[8*264 + i] = 0;  // slot pad rows

  s16x8 bq[2];
  #pragma unroll
  for (int ks = 0; ks < 2; ++ks)
    bq[ks] = *(const s16x8*)(qws + (b*16 + m16)*64 + ks*32 + q*8);

  #pragma unroll
  for (int mi = 0; mi < 4; ++mi){
    int n0 = (w*4 + mi)*16;
    f32x4 acc = {0.f, 0.f, 0.f, 0.f};
    #pragma unroll
    for (int ks = 0; ks < 2; ++ks){
      s16x8 af = *(const s16x8*)(kg + ((long)b*4096 + nbase + n0 + m16)*64 + ks*32 + q*8);
      acc = mfma16(af, bq[ks], acc);
    }
    #pragma unroll
    for (int rr = 0; rr < 4; ++rr)
      sc[(n0 + q*4 + rr)*17 + m16] = acc[rr];
  }
  __syncthreads();

  {
    int r = tid;
    float a8[8];
    float mx = -1e30f;
    #pragma unroll
    for (int j = 0; j < 8; ++j){ a8[j] = sc[r*17 + j]; mx = fmaxf(mx, a8[j]); }
    float ssum = 0.f;
    #pragma unroll
    for (int j = 0; j < 8; ++j){ a8[j] = expf(a8[j] - mx); ssum += a8[j]; }
    float inv = 1.f/ssum;
    #pragma unroll
    for (int j = 0; j < 8; ++j)
      aT[j*264 + r] = f2b(a8[j]*inv + 1e-8f);
  }
  __syncthreads();

  {  // S column sums (consistent with bf16-rounded aT used for U)
    int j = tid >> 5, c = tid & 31;
    float p = 0.f;
    #pragma unroll
    for (int i = 0; i < 8; ++i) p += b2f(aT[j*264 + c + 32*i]);
    #pragma unroll
    for (int m = 16; m >= 1; m >>= 1) p += __shfl_xor(p, m);
    if ((ln & 31) == 0) atomicAdd(&S[b*8 + j], p);
  }

  {  // U-partials: wave w handles h-tile nt = w
    f32x4 acc = {0.f, 0.f, 0.f, 0.f};
    #pragma unroll
    for (int ks = 0; ks < 8; ++ks){
      s16x8 af = *(const s16x8*)(aT + m16*264 + ks*32 + q*8);
      s16x8 bf = *(const s16x8*)(vt + ((long)b*64 + w*16 + m16)*4096 + nbase + ks*32 + q*8);
      acc = mfma16(af, bf, acc);
    }
    #pragma unroll
    for (int rr = 0; rr < 4; ++rr){
      int slot = q*4 + rr;
      if (slot < 8)
        atomicAdd(&U[b*512 + slot*64 + w*16 + m16], acc[rr]);
    }
  }
}

// ---------------------------------------------------------------------------
// K4: GRU + LN_mlp + MLP(+residual) + LN_sl + q for next iter. Weights f32,
// packed to bf16 fragments in-register. 16 blocks x 256 thr. f32 OUTPUT.
// ---------------------------------------------------------------------------
__global__ __launch_bounds__(256) void k_gru(
    const float* __restrict__ U, const float* __restrict__ S,
    float* __restrict__ slots,
    const float* __restrict__ wih, const float* __restrict__ whh,
    const float* __restrict__ bih, const float* __restrict__ bhh,
    const float* __restrict__ w1, const float* __restrict__ b1p,
    const float* __restrict__ w2, const float* __restrict__ b2p,
    const float* __restrict__ gmlp, const float* __restrict__ bmlp,
    const float* __restrict__ gsl, const float* __restrict__ bsl,
    const float* __restrict__ Wq,
    unsigned short* __restrict__ qws,
    float* __restrict__ outp,
    float* __restrict__ Uz, float* __restrict__ Sz)
{
  __shared__ unsigned short ut[16*72], ht[16*72], st[16*72], hid[16*136];
  __shared__ __align__(16) float redS[16][4];
  __shared__ __align__(16) float redQ[16][4];
  const int tid = threadIdx.x;
  const int w = tid >> 6, ln = tid & 63;
  const int m16 = ln & 15, q = ln >> 4;
  const int r0 = blockIdx.x * 16;
  const int cw = w*16 + m16;

  #pragma unroll
  for (int p = 0; p < 4; ++p){
    int row = p*4 + w;
    float sv = S[r0 + row];
    float uu = U[(r0 + row)*64 + ln] / sv;
    ut[row*72 + ln] = f2b(uu);
    ht[row*72 + ln] = f2b(slots[(r0 + row)*64 + ln]);
  }
  __syncthreads();

  f32x4 axr = {0,0,0,0}, axz = {0,0,0,0}, axn = {0,0,0,0};
  f32x4 ahr = {0,0,0,0}, ahz = {0,0,0,0}, ahn = {0,0,0,0};
  #pragma unroll
  for (int ks = 0; ks < 2; ++ks){
    s16x8 au = *(const s16x8*)(ut + m16*72 + ks*32 + q*8);
    s16x8 ah = *(const s16x8*)(ht + m16*72 + ks*32 + q*8);
    axr = mfma16(au, ld8f(wih + (      cw)*64 + ks*32 + q*8), axr);
    axz = mfma16(au, ld8f(wih + ( 64 + cw)*64 + ks*32 + q*8), axz);
    axn = mfma16(au, ld8f(wih + (128 + cw)*64 + ks*32 + q*8), axn);
    ahr = mfma16(ah, ld8f(whh + (      cw)*64 + ks*32 + q*8), ahr);
    ahz = mfma16(ah, ld8f(whh + ( 64 + cw)*64 + ks*32 + q*8), ahz);
    ahn = mfma16(ah, ld8f(whh + (128 + cw)*64 + ks*32 + q*8), ahn);
  }
  const float bxr = bih[cw], bxz = bih[64+cw], bxn = bih[128+cw];
  const float bhr = bhh[cw], bhz = bhh[64+cw], bhn = bhh[128+cw];
  float sp[4];
  #pragma unroll
  for (int rr = 0; rr < 4; ++rr){
    float xr = axr[rr] + bxr, xz = axz[rr] + bxz, xnv = axn[rr] + bxn;
    float hr = ahr[rr] + bhr, hz = ahz[rr] + bhz, hn = ahn[rr] + bhn;
    float rg = 1.f / (1.f + expf(-(xr + hr)));
    float zg = 1.f / (1.f + expf(-(xz + hz)));
    float ng = tanhf(xnv + rg*hn);
    float hv = b2f(ht[(q*4 + rr)*72 + cw]);
    sp[rr] = (1.f - zg)*ng + zg*hv;
  }

  // LN_mlp over the 64 cols of each row (quad-shuffle + cross-wave LDS reduce)
  float s1[4], s2[4];
  #pragma unroll
  for (int rr = 0; rr < 4; ++rr){ s1[rr] = sp[rr]; s2[rr] = sp[rr]*sp[rr]; }
  #pragma unroll
  for (int m = 1; m < 16; m <<= 1){
    #pragma unroll
    for (int rr = 0; rr < 4; ++rr){
      s1[rr] += __shfl_xor(s1[rr], m);
      s2[rr] += __shfl_xor(s2[rr], m);
    }
  }
  if (m16 == 0){
    #pragma unroll
    for (int rr = 0; rr < 4; ++rr){ redS[q*4+rr][w] = s1[rr]; redQ[q*4+rr][w] = s2[rr]; }
  }
  __syncthreads();
  float sl_[4];
  {
    const float gm = gmlp[cw], bm = bmlp[cw];
    #pragma unroll
    for (int rr = 0; rr < 4; ++rr){
      f32x4 aS = *(const f32x4*)redS[q*4+rr];
      f32x4 aQ = *(const f32x4*)redQ[q*4+rr];
      float tS = aS[0]+aS[1]+aS[2]+aS[3];
      float tQ = aQ[0]+aQ[1]+aQ[2]+aQ[3];
      float mean = tS*(1.f/64.f);
      float var  = tQ*(1.f/64.f) - mean*mean;
      float rs = rsqrtf(var + 1e-5f);
      sl_[rr] = (sp[rr] - mean)*rs*gm + bm;
      st[(q*4+rr)*72 + cw] = f2b(sl_[rr]);
    }
  }
  __syncthreads();

  // mlp1 (64->128) + relu
  #pragma unroll
  for (int t2 = 0; t2 < 2; ++t2){
    int nt = w*2 + t2;
    int col = nt*16 + m16;
    f32x4 acc = {0,0,0,0};
    #pragma unroll
    for (int ks = 0; ks < 2; ++ks){
      s16x8 a = *(const s16x8*)(st + m16*72 + ks*32 + q*8);
      acc = mfma16(a, ld8f(w1 + col*64 + ks*32 + q*8), acc);
    }
    float bb = b1p[col];
    #pragma unroll
    for (int rr = 0; rr < 4; ++rr)
      hid[(q*4+rr)*136 + col] = f2b(fmaxf(acc[rr] + bb, 0.f));
  }
  __syncthreads();

  // mlp2 (128->64) + residual
  float snew[4];
  {
    f32x4 acc = {0,0,0,0};
    #pragma unroll
    for (int ks = 0; ks < 4; ++ks){
      s16x8 a = *(const s16x8*)(hid + m16*136 + ks*32 + q*8);
      acc = mfma16(a, ld8f(w2 + cw*128 + ks*32 + q*8), acc);
    }
    float bb = b2p[cw];
    #pragma unroll
    for (int rr = 0; rr < 4; ++rr){
      snew[rr] = sl_[rr] + acc[rr] + bb;
      int row = r0 + q*4 + rr;
      slots[row*64 + cw] = snew[rr];
      outp[row*64 + cw] = snew[rr];          // f32 output
    }
  }

  // LN_sl(snew) -> q for next iteration
  #pragma unroll
  for (int rr = 0; rr < 4; ++rr){ s1[rr] = snew[rr]; s2[rr] = snew[rr]*snew[rr]; }
  #pragma unroll
  for (int m = 1; m < 16; m <<= 1){
    #pragma unroll
    for (int rr = 0; rr < 4; ++rr){
      s1[rr] += __shfl_xor(s1[rr], m);
      s2[rr] += __shfl_xor(s2[rr], m);
    }
  }
  __syncthreads();
  if (m16 == 0){
    #pragma unroll
    for (int rr = 0; rr < 4; ++rr){ redS[q*4+rr][w] = s1[rr]; redQ[q*4+rr][w] = s2[rr]; }
  }
  __syncthreads();
  {
    const float gs = gsl[cw], bs = bsl[cw];
    #pragma unroll
    for (int rr = 0; rr < 4; ++rr){
      f32x4 aS = *(const f32x4*)redS[q*4+rr];
      f32x4 aQ = *(const f32x4*)redQ[q*4+rr];
      float tS = aS[0]+aS[1]+aS[2]+aS[3];
      float tQ = aQ[0]+aQ[1]+aQ[2]+aQ[3];
      float mean = tS*(1.f/64.f);
      float var  = tQ*(1.f/64.f) - mean*mean;
      float rs = rsqrtf(var + 1e-5f);
      float sq = (snew[rr] - mean)*rs*gs + bs;
      st[(q*4+rr)*72 + cw] = f2b(sq);
    }
  }
  __syncthreads();
  {
    f32x4 acc = {0,0,0,0};
    #pragma unroll
    for (int ks = 0; ks < 2; ++ks){
      s16x8 a = *(const s16x8*)(st + m16*72 + ks*32 + q*8);
      acc = mfma16(a, ld8f(Wq + cw*64 + ks*32 + q*8), acc);
    }
    #pragma unroll
    for (int rr = 0; rr < 4; ++rr){
      int row = r0 + q*4 + rr;
      int bb_ = row >> 3, kk = row & 7;
      qws[(bb_*16 + kk)*64 + cw] = f2b(acc[rr] * 0.125f);
    }
  }
  // zero U,S for next iter + q slot-pads (all reads of U/S/qpads long done)
  {
    f32x4 z = {0,0,0,0};
    *(f32x4*)(Uz + r0*64 + tid*4) = z;
    if (tid < 16) Sz[r0 + tid] = 0.f;
    int b0 = blockIdx.x * 2;
    unsigned int* qp0 = (unsigned int*)(qws + (b0*16 + 8)*64);
    unsigned int* qp1 = (unsigned int*)(qws + ((b0+1)*16 + 8)*64);
    qp0[tid] = 0u;
    qp1[tid] = 0u;
  }
}

// ---------------------------------------------------------------------------
extern "C" void kernel_launch(void* const* d_in, const int* in_sizes, int n_in,
                              void* d_out, int out_size, void* d_ws, size_t ws_size,
                              hipStream_t stream)
{
  const float* x    = (const float*)d_in[0];
  const float* noise= (const float*)d_in[1];
  const float* Wq   = (const float*)d_in[2];
  const float* Wk   = (const float*)d_in[3];
  const float* Wv   = (const float*)d_in[4];
  const float* ling = (const float*)d_in[5];
  const float* linb = (const float*)d_in[6];
  const float* gsl  = (const float*)d_in[7];
  const float* bsl  = (const float*)d_in[8];
  const float* gmlp = (const float*)d_in[9];
  const float* bmlp = (const float*)d_in[10];
  const float* wih  = (const float*)d_in[11];
  const float* whh  = (const float*)d_in[12];
  const float* bih  = (const float*)d_in[13];
  const float* bhh  = (const float*)d_in[14];
  const float* w1   = (const float*)d_in[15];
  const float* b1p  = (const float*)d_in[16];
  const float* w2   = (const float*)d_in[17];
  const float* b2p  = (const float*)d_in[18];
  const float* mu   = (const float*)d_in[19];
  const float* lsg  = (const float*)d_in[20];

  char* ws = (char*)d_ws;
  unsigned short* kg   = (unsigned short*)(ws);              // 16 MiB: k [32][4096][64] bf16
  unsigned short* vt   = (unsigned short*)(ws + 16777216);   // 16 MiB: v^T [32][64][4096] bf16
  unsigned short* qws  = (unsigned short*)(ws + 33554432);   // 64 KiB: q [32][16][64] bf16 (slot-padded)
  float* slots         = (float*)(ws + 33619968);            // 64 KiB
  float* U             = (float*)(ws + 33685504);            // 64 KiB
  float* S             = (float*)(ws + 33751040);            // 1 KiB
  float* outp          = (float*)d_out;

  hipLaunchKernelGGL(k_lnkv, dim3(1024), dim3(256), 0, stream, x, Wk, Wv, ling, linb, kg, vt);
  hipLaunchKernelGGL(k_init, dim3(32), dim3(64), 0, stream, noise, mu, lsg, gsl, bsl, Wq, slots, qws, U, S);
  for (int it = 0; it < 3; ++it){
    hipLaunchKernelGGL(k_attn, dim3(512), dim3(256), 0, stream, kg, vt, qws, U, S);
    hipLaunchKernelGGL(k_gru, dim3(16), dim3(256), 0, stream, U, S, slots,
                       wih, whh, bih, bhh, w1, b1p, w2, b2p, gmlp, bmlp, gsl, bsl, Wq,
                       qws, outp, U, S);
  }
  (void)in_sizes; (void)n_in; (void)out_size; (void)ws_size;
}

// Round 6
// 249.560 us; speedup vs baseline: 4.4850x; 1.1364x over previous
//
#include <hip/hip_runtime.h>

typedef __attribute__((ext_vector_type(8))) short s16x8;
typedef __attribute__((ext_vector_type(4))) float f32x4;

#define DEV static __device__ __forceinline__

DEV float b2f(unsigned short u){
  unsigned int i = ((unsigned int)u) << 16;
  float f; __builtin_memcpy(&f, &i, 4); return f;
}
DEV unsigned short f2b(float f){
  unsigned int i; __builtin_memcpy(&i, &f, 4);
  i = i + 0x7fffu + ((i >> 16) & 1u);
  return (unsigned short)(i >> 16);
}
DEV f32x4 mfma16(s16x8 a, s16x8 b, f32x4 c){
  return __builtin_amdgcn_mfma_f32_16x16x32_bf16(a, b, c, 0, 0, 0);
}
// load 8 consecutive f32 (32B-aligned) -> bf16 A/B fragment
DEV s16x8 ld8f(const float* p){
  const float4* q4 = (const float4*)p;
  float4 a = q4[0], b = q4[1];
  s16x8 r;
  r[0]=(short)f2b(a.x); r[1]=(short)f2b(a.y); r[2]=(short)f2b(a.z); r[3]=(short)f2b(a.w);
  r[4]=(short)f2b(b.x); r[5]=(short)f2b(b.y); r[6]=(short)f2b(b.z); r[7]=(short)f2b(b.w);
  return r;
}

// ---------------------------------------------------------------------------
// K1: LN(x) -> k = xn@Wk^T (plain [b][n][h] bf16), v = xn@Wv^T (transposed
// [b][h][n] bf16). 1024 blocks x 256 thr, 128 rows/block.
// Phase 1 rework: float4/lane (half-wave per row), 4 batched loads in flight
// -> 8x memory-level parallelism vs round 5 (which measured 672 GB/s,
// latency-bound at 1 load/wave in flight).
// ---------------------------------------------------------------------------
__global__ __launch_bounds__(256) void k_lnkv(
    const float* __restrict__ x,
    const float* __restrict__ Wk,
    const float* __restrict__ Wv,
    const float* __restrict__ lg,
    const float* __restrict__ lb,
    unsigned short* __restrict__ kg,
    unsigned short* __restrict__ vt)
{
  __shared__ unsigned int xs[128 * 68];   // 128 rows x (64 data + 4 pad) uints (bf16 pairs)
  const int tid = threadIdx.x;
  const int w = tid >> 6, ln = tid & 63;
  const int m16 = ln & 15, q = ln >> 4;
  const int b = blockIdx.x >> 5;
  const int nbase = (blockIdx.x & 31) << 7;
  const long rowg0 = (long)b * 4096 + nbase;

  // phase 1: LN(x) -> LDS bf16. Lane covers elements 4L..4L+3 of its row;
  // half-wave (32 lanes) per row, two rows per wave-load.
  {
    const int half = ln >> 5;      // 0/1: row parity within pair
    const int L = ln & 31;
    const float4 gl4 = *(const float4*)(lg + L*4);
    const float4 bl4 = *(const float4*)(lb + L*4);
    for (int i = 0; i < 16; i += 4){
      float4 xv[4];
      #pragma unroll
      for (int j = 0; j < 4; ++j){
        int r = w*32 + (i+j)*2 + half;
        xv[j] = *(const float4*)(x + (rowg0 + r)*128 + L*4);
      }
      #pragma unroll
      for (int j = 0; j < 4; ++j){
        int r = w*32 + (i+j)*2 + half;
        float4 v = xv[j];
        float s1 = v.x + v.y + v.z + v.w;
        float s2 = v.x*v.x + v.y*v.y + v.z*v.z + v.w*v.w;
        #pragma unroll
        for (int m = 16; m >= 1; m >>= 1){
          s1 += __shfl_xor(s1, m);
          s2 += __shfl_xor(s2, m);
        }
        float mean = s1 * (1.f/128.f);
        float var  = s2 * (1.f/128.f) - mean*mean;
        float rs = rsqrtf(var + 1e-5f);
        float y0 = (v.x - mean)*rs*gl4.x + bl4.x;
        float y1 = (v.y - mean)*rs*gl4.y + bl4.y;
        float y2 = (v.z - mean)*rs*gl4.z + bl4.z;
        float y3 = (v.w - mean)*rs*gl4.w + bl4.w;
        uint2 pk;
        pk.x = (unsigned int)f2b(y0) | ((unsigned int)f2b(y1) << 16);
        pk.y = (unsigned int)f2b(y2) | ((unsigned int)f2b(y3) << 16);
        *(uint2*)&xs[r*68 + L*2] = pk;   // word 2L holds elems 4L,4L+1 (same layout as before)
      }
    }
  }
  __syncthreads();

  // B-fragments: B[k=d][n'=h'] = Wc[h'][d]; nt 0..3 -> Wk rows, 4..7 -> Wv rows
  s16x8 bw[4][8];
  #pragma unroll
  for (int nt = 0; nt < 8; ++nt){
    const float* Wp = (nt < 4) ? (Wk + (nt*16 + m16)*128)
                               : (Wv + ((nt-4)*16 + m16)*128);
    #pragma unroll
    for (int kb = 0; kb < 4; ++kb)
      bw[kb][nt] = ld8f(Wp + kb*32 + q*8);
  }

  const f32x4 zf = {0.f, 0.f, 0.f, 0.f};
  #pragma unroll
  for (int mi = 0; mi < 2; ++mi){
    int n0 = (w*2 + mi) * 16;
    f32x4 acc[8];
    #pragma unroll
    for (int nt = 0; nt < 8; ++nt) acc[nt] = zf;
    #pragma unroll
    for (int kb = 0; kb < 4; ++kb){
      s16x8 af = *(const s16x8*)((const unsigned short*)(xs + (n0 + m16)*68) + kb*32 + q*8);
      #pragma unroll
      for (int nt = 0; nt < 8; ++nt)
        acc[nt] = mfma16(af, bw[kb][nt], acc[nt]);
    }
    // k: plain [b][n][h]; D row = q*4+rr, col = nt*16+m16
    #pragma unroll
    for (int nt = 0; nt < 4; ++nt){
      int h = nt*16 + m16;
      #pragma unroll
      for (int rr = 0; rr < 4; ++rr){
        long n = rowg0 + n0 + q*4 + rr;
        kg[n*64 + h] = f2b(acc[nt][rr]);
      }
    }
    // v: transposed [b][h][n]; the 4 regs are consecutive n -> one 8B store
    #pragma unroll
    for (int nt = 4; nt < 8; ++nt){
      int h = (nt-4)*16 + m16;
      unsigned int p0 = (unsigned int)f2b(acc[nt][0]) | ((unsigned int)f2b(acc[nt][1]) << 16);
      unsigned int p1 = (unsigned int)f2b(acc[nt][2]) | ((unsigned int)f2b(acc[nt][3]) << 16);
      uint2 pv; pv.x = p0; pv.y = p1;
      long off = ((long)b*64 + h)*4096 + nbase + n0 + q*4;
      *(uint2*)(vt + off) = pv;
    }
  }
}

// ---------------------------------------------------------------------------
// K2 (rework): slot init + LN_sl + q0 via MFMA, k_gru-tail pattern.
// 16 blocks x 256 thr; block = 16 rows of (b,k). Replaces the single-wave
// 64-deep gather loop of round 5 (serial-latency-bound).
// ---------------------------------------------------------------------------
__global__ __launch_bounds__(256) void k_init2(
    const float* __restrict__ noise,
    const float* __restrict__ mu,
    const float* __restrict__ lsg,
    const float* __restrict__ gsl,
    const float* __restrict__ bsl,
    const float* __restrict__ Wq,
    float* __restrict__ slots,
    unsigned short* __restrict__ qws,
    float* __restrict__ U, float* __restrict__ S)
{
  __shared__ unsigned short st[16*72];
  __shared__ __align__(16) float redS[16][4];
  __shared__ __align__(16) float redQ[16][4];
  const int tid = threadIdx.x;
  const int w = tid >> 6, ln = tid & 63;
  const int m16 = ln & 15, q = ln >> 4;
  const int r0 = blockIdx.x * 16;
  const int cw = w*16 + m16;

  float sl[4], s1[4], s2[4];
  #pragma unroll
  for (int rr = 0; rr < 4; ++rr){
    int row = r0 + q*4 + rr;
    int k = row & 7;
    float v = mu[k*64 + cw] + (log1pf(expf(lsg[k*64 + cw])) + 1e-5f) * noise[row*64 + cw];
    sl[rr] = v;
    slots[row*64 + cw] = v;
    s1[rr] = v; s2[rr] = v*v;
  }
  #pragma unroll
  for (int m = 1; m < 16; m <<= 1){
    #pragma unroll
    for (int rr = 0; rr < 4; ++rr){
      s1[rr] += __shfl_xor(s1[rr], m);
      s2[rr] += __shfl_xor(s2[rr], m);
    }
  }
  if (m16 == 0){
    #pragma unroll
    for (int rr = 0; rr < 4; ++rr){ redS[q*4+rr][w] = s1[rr]; redQ[q*4+rr][w] = s2[rr]; }
  }
  __syncthreads();
  {
    const float gs = gsl[cw], bs = bsl[cw];
    #pragma unroll
    for (int rr = 0; rr < 4; ++rr){
      f32x4 aS = *(const f32x4*)redS[q*4+rr];
      f32x4 aQ = *(const f32x4*)redQ[q*4+rr];
      float tS = aS[0]+aS[1]+aS[2]+aS[3];
      float tQ = aQ[0]+aQ[1]+aQ[2]+aQ[3];
      float mean = tS*(1.f/64.f);
      float var  = tQ*(1.f/64.f) - mean*mean;
      float rs = rsqrtf(var + 1e-5f);
      float sq = (sl[rr] - mean)*rs*gs + bs;
      st[(q*4+rr)*72 + cw] = f2b(sq);
    }
  }
  __syncthreads();
  {
    f32x4 acc = {0,0,0,0};
    #pragma unroll
    for (int ks = 0; ks < 2; ++ks){
      s16x8 a = *(const s16x8*)(st + m16*72 + ks*32 + q*8);
      acc = mfma16(a, ld8f(Wq + cw*64 + ks*32 + q*8), acc);
    }
    #pragma unroll
    for (int rr = 0; rr < 4; ++rr){
      int row = r0 + q*4 + rr;
      int bb_ = row >> 3, kk = row & 7;
      qws[(bb_*16 + kk)*64 + cw] = f2b(acc[rr] * 0.125f);
    }
  }
  // zero U, S, q slot-pads
  {
    f32x4 z = {0,0,0,0};
    *(f32x4*)(U + r0*64 + tid*4) = z;
    if (tid < 16) S[r0 + tid] = 0.f;
    int b0 = blockIdx.x * 2;
    ((unsigned int*)(qws + (b0*16 + 8)*64))[tid] = 0u;
    ((unsigned int*)(qws + ((b0+1)*16 + 8)*64))[tid] = 0u;
  }
}

// ---------------------------------------------------------------------------
// K3: attention pass (UNCHANGED from round 5). 512 blocks x 256 thr.
// ---------------------------------------------------------------------------
__global__ __launch_bounds__(256) void k_attn(
    const unsigned short* __restrict__ kg,
    const unsigned short* __restrict__ vt,
    const unsigned short* __restrict__ qws,
    float* __restrict__ U, float* __restrict__ S)
{
  __shared__ float sc[256*17];
  __shared__ unsigned short aT[16*264];   // stride 264 (=16B-aligned rows)
  const int tid = threadIdx.x;
  const int w = tid >> 6, ln = tid & 63;
  const int m16 = ln & 15, q = ln >> 4;
  const int b = blockIdx.x >> 4;
  const int nbase = (blockIdx.x & 15) << 8;

  for (int i = tid; i < 8*264; i += 256) aT[8*264 + i] = 0;  // slot pad rows

  s16x8 bq[2];
  #pragma unroll
  for (int ks = 0; ks < 2; ++ks)
    bq[ks] = *(const s16x8*)(qws + (b*16 + m16)*64 + ks*32 + q*8);

  #pragma unroll
  for (int mi = 0; mi < 4; ++mi){
    int n0 = (w*4 + mi)*16;
    f32x4 acc = {0.f, 0.f, 0.f, 0.f};
    #pragma unroll
    for (int ks = 0; ks < 2; ++ks){
      s16x8 af = *(const s16x8*)(kg + ((long)b*4096 + nbase + n0 + m16)*64 + ks*32 + q*8);
      acc = mfma16(af, bq[ks], acc);
    }
    #pragma unroll
    for (int rr = 0; rr < 4; ++rr)
      sc[(n0 + q*4 + rr)*17 + m16] = acc[rr];
  }
  __syncthreads();

  {
    int r = tid;
    float a8[8];
    float mx = -1e30f;
    #pragma unroll
    for (int j = 0; j < 8; ++j){ a8[j] = sc[r*17 + j]; mx = fmaxf(mx, a8[j]); }
    float ssum = 0.f;
    #pragma unroll
    for (int j = 0; j < 8; ++j){ a8[j] = expf(a8[j] - mx); ssum += a8[j]; }
    float inv = 1.f/ssum;
    #pragma unroll
    for (int j = 0; j < 8; ++j)
      aT[j*264 + r] = f2b(a8[j]*inv + 1e-8f);
  }
  __syncthreads();

  {  // S column sums (consistent with bf16-rounded aT used for U)
    int j = tid >> 5, c = tid & 31;
    float p = 0.f;
    #pragma unroll
    for (int i = 0; i < 8; ++i) p += b2f(aT[j*264 + c + 32*i]);
    #pragma unroll
    for (int m = 16; m >= 1; m >>= 1) p += __shfl_xor(p, m);
    if ((ln & 31) == 0) atomicAdd(&S[b*8 + j], p);
  }

  {  // U-partials: wave w handles h-tile nt = w
    f32x4 acc = {0.f, 0.f, 0.f, 0.f};
    #pragma unroll
    for (int ks = 0; ks < 8; ++ks){
      s16x8 af = *(const s16x8*)(aT + m16*264 + ks*32 + q*8);
      s16x8 bf = *(const s16x8*)(vt + ((long)b*64 + w*16 + m16)*4096 + nbase + ks*32 + q*8);
      acc = mfma16(af, bf, acc);
    }
    #pragma unroll
    for (int rr = 0; rr < 4; ++rr){
      int slot = q*4 + rr;
      if (slot < 8)
        atomicAdd(&U[b*512 + slot*64 + w*16 + m16], acc[rr]);
    }
  }
}

// ---------------------------------------------------------------------------
// K4: GRU + LN_mlp + MLP(+residual) + LN_sl + q for next iter (UNCHANGED).
// ---------------------------------------------------------------------------
__global__ __launch_bounds__(256) void k_gru(
    const float* __restrict__ U, const float* __restrict__ S,
    float* __restrict__ slots,
    const float* __restrict__ wih, const float* __restrict__ whh,
    const float* __restrict__ bih, const float* __restrict__ bhh,
    const float* __restrict__ w1, const float* __restrict__ b1p,
    const float* __restrict__ w2, const float* __restrict__ b2p,
    const float* __restrict__ gmlp, const float* __restrict__ bmlp,
    const float* __restrict__ gsl, const float* __restrict__ bsl,
    const float* __restrict__ Wq,
    unsigned short* __restrict__ qws,
    float* __restrict__ outp,
    float* __restrict__ Uz, float* __restrict__ Sz)
{
  __shared__ unsigned short ut[16*72], ht[16*72], st[16*72], hid[16*136];
  __shared__ __align__(16) float redS[16][4];
  __shared__ __align__(16) float redQ[16][4];
  const int tid = threadIdx.x;
  const int w = tid >> 6, ln = tid & 63;
  const int m16 = ln & 15, q = ln >> 4;
  const int r0 = blockIdx.x * 16;
  const int cw = w*16 + m16;

  #pragma unroll
  for (int p = 0; p < 4; ++p){
    int row = p*4 + w;
    float sv = S[r0 + row];
    float uu = U[(r0 + row)*64 + ln] / sv;
    ut[row*72 + ln] = f2b(uu);
    ht[row*72 + ln] = f2b(slots[(r0 + row)*64 + ln]);
  }
  __syncthreads();

  f32x4 axr = {0,0,0,0}, axz = {0,0,0,0}, axn = {0,0,0,0};
  f32x4 ahr = {0,0,0,0}, ahz = {0,0,0,0}, ahn = {0,0,0,0};
  #pragma unroll
  for (int ks = 0; ks < 2; ++ks){
    s16x8 au = *(const s16x8*)(ut + m16*72 + ks*32 + q*8);
    s16x8 ah = *(const s16x8*)(ht + m16*72 + ks*32 + q*8);
    axr = mfma16(au, ld8f(wih + (      cw)*64 + ks*32 + q*8), axr);
    axz = mfma16(au, ld8f(wih + ( 64 + cw)*64 + ks*32 + q*8), axz);
    axn = mfma16(au, ld8f(wih + (128 + cw)*64 + ks*32 + q*8), axn);
    ahr = mfma16(ah, ld8f(whh + (      cw)*64 + ks*32 + q*8), ahr);
    ahz = mfma16(ah, ld8f(whh + ( 64 + cw)*64 + ks*32 + q*8), ahz);
    ahn = mfma16(ah, ld8f(whh + (128 + cw)*64 + ks*32 + q*8), ahn);
  }
  const float bxr = bih[cw], bxz = bih[64+cw], bxn = bih[128+cw];
  const float bhr = bhh[cw], bhz = bhh[64+cw], bhn = bhh[128+cw];
  float sp[4];
  #pragma unroll
  for (int rr = 0; rr < 4; ++rr){
    float xr = axr[rr] + bxr, xz = axz[rr] + bxz, xnv = axn[rr] + bxn;
    float hr = ahr[rr] + bhr, hz = ahz[rr] + bhz, hn = ahn[rr] + bhn;
    float rg = 1.f / (1.f + expf(-(xr + hr)));
    float zg = 1.f / (1.f + expf(-(xz + hz)));
    float ng = tanhf(xnv + rg*hn);
    float hv = b2f(ht[(q*4 + rr)*72 + cw]);
    sp[rr] = (1.f - zg)*ng + zg*hv;
  }

  // LN_mlp over the 64 cols of each row (quad-shuffle + cross-wave LDS reduce)
  float s1[4], s2[4];
  #pragma unroll
  for (int rr = 0; rr < 4; ++rr){ s1[rr] = sp[rr]; s2[rr] = sp[rr]*sp[rr]; }
  #pragma unroll
  for (int m = 1; m < 16; m <<= 1){
    #pragma unroll
    for (int rr = 0; rr < 4; ++rr){
      s1[rr] += __shfl_xor(s1[rr], m);
      s2[rr] += __shfl_xor(s2[rr], m);
    }
  }
  if (m16 == 0){
    #pragma unroll
    for (int rr = 0; rr < 4; ++rr){ redS[q*4+rr][w] = s1[rr]; redQ[q*4+rr][w] = s2[rr]; }
  }
  __syncthreads();
  float sl_[4];
  {
    const float gm = gmlp[cw], bm = bmlp[cw];
    #pragma unroll
    for (int rr = 0; rr < 4; ++rr){
      f32x4 aS = *(const f32x4*)redS[q*4+rr];
      f32x4 aQ = *(const f32x4*)redQ[q*4+rr];
      float tS = aS[0]+aS[1]+aS[2]+aS[3];
      float tQ = aQ[0]+aQ[1]+aQ[2]+aQ[3];
      float mean = tS*(1.f/64.f);
      float var  = tQ*(1.f/64.f) - mean*mean;
      float rs = rsqrtf(var + 1e-5f);
      sl_[rr] = (sp[rr] - mean)*rs*gm + bm;
      st[(q*4+rr)*72 + cw] = f2b(sl_[rr]);
    }
  }
  __syncthreads();

  // mlp1 (64->128) + relu
  #pragma unroll
  for (int t2 = 0; t2 < 2; ++t2){
    int nt = w*2 + t2;
    int col = nt*16 + m16;
    f32x4 acc = {0,0,0,0};
    #pragma unroll
    for (int ks = 0; ks < 2; ++ks){
      s16x8 a = *(const s16x8*)(st + m16*72 + ks*32 + q*8);
      acc = mfma16(a, ld8f(w1 + col*64 + ks*32 + q*8), acc);
    }
    float bb = b1p[col];
    #pragma unroll
    for (int rr = 0; rr < 4; ++rr)
      hid[(q*4+rr)*136 + col] = f2b(fmaxf(acc[rr] + bb, 0.f));
  }
  __syncthreads();

  // mlp2 (128->64) + residual
  float snew[4];
  {
    f32x4 acc = {0,0,0,0};
    #pragma unroll
    for (int ks = 0; ks < 4; ++ks){
      s16x8 a = *(const s16x8*)(hid + m16*136 + ks*32 + q*8);
      acc = mfma16(a, ld8f(w2 + cw*128 + ks*32 + q*8), acc);
    }
    float bb = b2p[cw];
    #pragma unroll
    for (int rr = 0; rr < 4; ++rr){
      snew[rr] = sl_[rr] + acc[rr] + bb;
      int row = r0 + q*4 + rr;
      slots[row*64 + cw] = snew[rr];
      outp[row*64 + cw] = snew[rr];          // f32 output
    }
  }

  // LN_sl(snew) -> q for next iteration
  #pragma unroll
  for (int rr = 0; rr < 4; ++rr){ s1[rr] = snew[rr]; s2[rr] = snew[rr]*snew[rr]; }
  #pragma unroll
  for (int m = 1; m < 16; m <<= 1){
    #pragma unroll
    for (int rr = 0; rr < 4; ++rr){
      s1[rr] += __shfl_xor(s1[rr], m);
      s2[rr] += __shfl_xor(s2[rr], m);
    }
  }
  __syncthreads();
  if (m16 == 0){
    #pragma unroll
    for (int rr = 0; rr < 4; ++rr){ redS[q*4+rr][w] = s1[rr]; redQ[q*4+rr][w] = s2[rr]; }
  }
  __syncthreads();
  {
    const float gs = gsl[cw], bs = bsl[cw];
    #pragma unroll
    for (int rr = 0; rr < 4; ++rr){
      f32x4 aS = *(const f32x4*)redS[q*4+rr];
      f32x4 aQ = *(const f32x4*)redQ[q*4+rr];
      float tS = aS[0]+aS[1]+aS[2]+aS[3];
      float tQ = aQ[0]+aQ[1]+aQ[2]+aQ[3];
      float mean = tS*(1.f/64.f);
      float var  = tQ*(1.f/64.f) - mean*mean;
      float rs = rsqrtf(var + 1e-5f);
      float sq = (snew[rr] - mean)*rs*gs + bs;
      st[(q*4+rr)*72 + cw] = f2b(sq);
    }
  }
  __syncthreads();
  {
    f32x4 acc = {0,0,0,0};
    #pragma unroll
    for (int ks = 0; ks < 2; ++ks){
      s16x8 a = *(const s16x8*)(st + m16*72 + ks*32 + q*8);
      acc = mfma16(a, ld8f(Wq + cw*64 + ks*32 + q*8), acc);
    }
    #pragma unroll
    for (int rr = 0; rr < 4; ++rr){
      int row = r0 + q*4 + rr;
      int bb_ = row >> 3, kk = row & 7;
      qws[(bb_*16 + kk)*64 + cw] = f2b(acc[rr] * 0.125f);
    }
  }
  // zero U,S for next iter + q slot-pads (all reads of U/S/qpads long done)
  {
    f32x4 z = {0,0,0,0};
    *(f32x4*)(Uz + r0*64 + tid*4) = z;
    if (tid < 16) Sz[r0 + tid] = 0.f;
    int b0 = blockIdx.x * 2;
    unsigned int* qp0 = (unsigned int*)(qws + (b0*16 + 8)*64);
    unsigned int* qp1 = (unsigned int*)(qws + ((b0+1)*16 + 8)*64);
    qp0[tid] = 0u;
    qp1[tid] = 0u;
  }
}

// ---------------------------------------------------------------------------
extern "C" void kernel_launch(void* const* d_in, const int* in_sizes, int n_in,
                              void* d_out, int out_size, void* d_ws, size_t ws_size,
                              hipStream_t stream)
{
  const float* x    = (const float*)d_in[0];
  const float* noise= (const float*)d_in[1];
  const float* Wq   = (const float*)d_in[2];
  const float* Wk   = (const float*)d_in[3];
  const float* Wv   = (const float*)d_in[4];
  const float* ling = (const float*)d_in[5];
  const float* linb = (const float*)d_in[6];
  const float* gsl  = (const float*)d_in[7];
  const float* bsl  = (const float*)d_in[8];
  const float* gmlp = (const float*)d_in[9];
  const float* bmlp = (const float*)d_in[10];
  const float* wih  = (const float*)d_in[11];
  const float* whh  = (const float*)d_in[12];
  const float* bih  = (const float*)d_in[13];
  const float* bhh  = (const float*)d_in[14];
  const float* w1   = (const float*)d_in[15];
  const float* b1p  = (const float*)d_in[16];
  const float* w2   = (const float*)d_in[17];
  const float* b2p  = (const float*)d_in[18];
  const float* mu   = (const float*)d_in[19];
  const float* lsg  = (const float*)d_in[20];

  char* ws = (char*)d_ws;
  unsigned short* kg   = (unsigned short*)(ws);              // 16 MiB: k [32][4096][64] bf16
  unsigned short* vt   = (unsigned short*)(ws + 16777216);   // 16 MiB: v^T [32][64][4096] bf16
  unsigned short* qws  = (unsigned short*)(ws + 33554432);   // 64 KiB: q [32][16][64] bf16 (slot-padded)
  float* slots         = (float*)(ws + 33619968);            // 64 KiB
  float* U             = (float*)(ws + 33685504);            // 64 KiB
  float* S             = (float*)(ws + 33751040);            // 1 KiB
  float* outp          = (float*)d_out;

  hipLaunchKernelGGL(k_lnkv, dim3(1024), dim3(256), 0, stream, x, Wk, Wv, ling, linb, kg, vt);
  hipLaunchKernelGGL(k_init2, dim3(16), dim3(256), 0, stream, noise, mu, lsg, gsl, bsl, Wq, slots, qws, U, S);
  for (int it = 0; it < 3; ++it){
    hipLaunchKernelGGL(k_attn, dim3(512), dim3(256), 0, stream, kg, vt, qws, U, S);
    hipLaunchKernelGGL(k_gru, dim3(16), dim3(256), 0, stream, U, S, slots,
                       wih, whh, bih, bhh, w1, b1p, w2, b2p, gmlp, bmlp, gsl, bsl, Wq,
                       qws, outp, U, S);
  }
  (void)in_sizes; (void)n_in; (void)out_size; (void)ws_size;
}